// Round 3
// baseline (433.209 us; speedup 1.0000x reference)
//
#include <hip/hip_runtime.h>
#include <hip/hip_bf16.h>
#include <stdint.h>

#define IN_F  4096
#define OUT_F 4096
#define BSZ   4
#define SEQ   2048
#define MDIM  (BSZ * SEQ)   // 8192

// ---------------- address-space helpers for global_load_lds ----------------
typedef __attribute__((address_space(1))) uint8_t ga_u8_t;
typedef __attribute__((address_space(3))) uint8_t ls_u8_t;

__device__ __forceinline__ void gload16_lds(const void* g, void* l) {
    // 16B-wide direct global->LDS DMA (global_load_lds_dwordx4)
    __builtin_amdgcn_global_load_lds((ga_u8_t*)g, (ls_u8_t*)l, 16, 0, 0);
}

// round-to-nearest-even fp32 -> bf16, returned as fp32 value
__device__ __forceinline__ float bf16_rne(float f) {
    unsigned u = __float_as_uint(f);
    u = (u + 0x7fffu + ((u >> 16) & 1u)) & 0xffff0000u;
    return __uint_as_float(u);
}

// ---------------- pass 1: global amax of |x| ----------------
__global__ void amax_kernel(const float* __restrict__ x, int n4,
                            unsigned int* __restrict__ amax_u) {
    const float4* x4 = (const float4*)x;
    int idx = blockIdx.x * blockDim.x + threadIdx.x;
    int stride = gridDim.x * blockDim.x;
    float m = 0.0f;
    for (int i = idx; i < n4; i += stride) {
        float4 v = x4[i];
        m = fmaxf(m, fmaxf(fmaxf(fabsf(v.x), fabsf(v.y)),
                           fmaxf(fabsf(v.z), fabsf(v.w))));
    }
    for (int off = 32; off > 0; off >>= 1)
        m = fmaxf(m, __shfl_down(m, off, 64));
    __shared__ float sm[4];
    int lane = threadIdx.x & 63, wave = threadIdx.x >> 6;
    if (lane == 0) sm[wave] = m;
    __syncthreads();
    if (threadIdx.x == 0) {
        m = fmaxf(fmaxf(sm[0], sm[1]), fmaxf(sm[2], sm[3]));
        atomicMax(amax_u, __float_as_uint(m));  // valid: all values >= 0
    }
}

// ---------------- pass 2: quantize x -> int8 AND repack w -> int8 ----------
__global__ void prep_kernel(const float* __restrict__ x,
                            const int* __restrict__ w,
                            signed char* __restrict__ x8,
                            signed char* __restrict__ w8,
                            const unsigned int* __restrict__ amax_u,
                            int nx4, int nw4) {
    int idx = blockIdx.x * blockDim.x + threadIdx.x;
    if (idx < nx4) {
        float amax = __uint_as_float(*amax_u);
        float xs = (amax == 0.0f) ? 1.0f : (amax / 127.0f);  // ref: amax/127
        float4 v = ((const float4*)x)[idx];
        char4 q;
        q.x = (signed char)fminf(fmaxf(rintf(v.x / xs), -127.0f), 127.0f);
        q.y = (signed char)fminf(fmaxf(rintf(v.y / xs), -127.0f), 127.0f);
        q.z = (signed char)fminf(fmaxf(rintf(v.z / xs), -127.0f), 127.0f);
        q.w = (signed char)fminf(fmaxf(rintf(v.w / xs), -127.0f), 127.0f);
        ((char4*)x8)[idx] = q;
    } else {
        int widx = idx - nx4;
        if (widx < nw4) {
            int4 v = ((const int4*)w)[widx];
            char4 q;
            q.x = (signed char)v.x; q.y = (signed char)v.y;
            q.z = (signed char)v.z; q.w = (signed char)v.w;
            ((char4*)w8)[widx] = q;
        }
    }
}

// ---------------- pass 3: int8 GEMM, 256x256 tile, 1 barrier/tile ---------
// R3: R2's manual lgkm counts + sched_barrier pins regressed (compiler
// already fine-schedules plain ds_reads; pins only removed its freedom --
// the m141 failure mode). R1's real cost was 8 barriers/tile forcing
// [reads] -> [MFMA] lockstep (LDS and matrix pipes alternate, never overlap;
// only 2 waves/SIMD resident to hide anything).
// With TRIPLE buffering the only cross-wave hazard is staging T+2
// overwriting buf (T-1)%3, whose reads all returned before each wave's last
// MFMA of tile T-1 (lgkm waits precede MFMA issue). So: ONE barrier per
// tile, then {issue 4 staging units; vmcnt(4); 12 ds_reads; 32 MFMAs} as a
// single unpinned region. Counted vmcnt invariant: at tile T the wait
// drains stage(T+1) (confirming NEXT tile's buffer one tile early); buf T
// was confirmed at tile T-1. Loads never drain to 0 in the main loop.
using i32x4 = __attribute__((ext_vector_type(4))) int;

#define FENCE() asm volatile("" ::: "memory")
#define BAR()   do { FENCE(); __builtin_amdgcn_s_barrier(); FENCE(); } while (0)
#define WAITV(N) asm volatile("s_waitcnt vmcnt(" #N ")" ::: "memory")

// One K-tile. BUF/SBUF are compile-time buffer indices (0/1/2); KST is the
// global k byte offset staged (tile T+2). WV: per-tile counted vmcnt.
// No lgkm waits, no sched_barriers: compiler interleaves reads and MFMAs.
#define TILE1(BUF, SBUF, KST, DOSTAGE, WV)                                   \
  {                                                                          \
    const signed char* base = smem + (BUF) * 32768;                          \
    BAR();                                                                   \
    if (DOSTAGE) {                                                           \
        signed char* sb = smem + (SBUF) * 32768;                             \
        gload16_lds(gA0 + (KST), sb + dA0);                                  \
        gload16_lds(gA1 + (KST), sb + dA1);                                  \
        gload16_lds(gB0 + (KST), sb + dB0);                                  \
        gload16_lds(gB1 + (KST), sb + dB1);                                  \
    }                                                                        \
    WV;                                                                      \
    i32x4 bF[4], aF[8];                                                      \
    _Pragma("unroll")                                                        \
    for (int j = 0; j < 4; ++j) bF[j] = *(const i32x4*)(base + boff[j]);     \
    _Pragma("unroll")                                                        \
    for (int i = 0; i < 8; ++i) aF[i] = *(const i32x4*)(base + aoff[i]);     \
    _Pragma("unroll")                                                        \
    for (int i = 0; i < 8; ++i)                                              \
      _Pragma("unroll")                                                      \
      for (int j = 0; j < 4; ++j)                                            \
        acc[i][j] = __builtin_amdgcn_mfma_i32_16x16x64_i8(                   \
            aF[i], bF[j], acc[i][j], 0, 0, 0);                               \
  }

__global__ __launch_bounds__(512, 2) void gemm_i8_kernel(
    const signed char* __restrict__ A,
    const signed char* __restrict__ B,
    const unsigned int* __restrict__ amax_u,
    const float* __restrict__ wscale_p,
    const float* __restrict__ bias,
    float* __restrict__ out) {
    __shared__ signed char smem[3 * 32768];  // 96 KB: 3 K-tile buffers

    const int tid = threadIdx.x;      // 0..511
    const int lane = tid & 63;
    const int wave = tid >> 6;        // 0..7
    const int wm = wave >> 2;         // 0..1
    const int wn = wave & 3;          // 0..3

    // Bijective XCD swizzle: 512 blocks, 8 XCDs, chunk = 64 = 4 mt x 16 nt.
    const int bid = blockIdx.x;
    const int wg = (bid & 7) * 64 + (bid >> 3);
    const int mt = wg >> 4;           // 0..31
    const int nt = wg & 15;           // 0..15
    const int tileM = mt * 256;
    const int tileN = nt * 256;

    // Staging: 4 units per K-tile, each 8KB = 512 threads x 16B.
    // LDS dst linear (g*16); swizzle applied on the GLOBAL source column:
    // LDS(row, c) holds G(row, c ^ ((row>>1)&3)).
    const int g = tid;
    const int srow = g >> 2;                              // 0..127
    const int scol = ((g & 3) ^ ((srow >> 1) & 3)) * 16;  // pre-swizzled
    const signed char* gA0 = A + (size_t)(tileM +       srow) * IN_F + scol;
    const signed char* gA1 = A + (size_t)(tileM + 128 + srow) * IN_F + scol;
    const signed char* gB0 = B + (size_t)(tileN +       srow) * IN_F + scol;
    const signed char* gB1 = B + (size_t)(tileN + 128 + srow) * IN_F + scol;
    const int dA0 = g * 16;
    const int dA1 = 8192  + g * 16;
    const int dB0 = 16384 + g * 16;
    const int dB1 = 24576 + g * 16;

    // Fragment LDS offsets (within one buffer). A frag: m = lane&15,
    // k-chunk = lane>>4; read col = kc ^ ((row>>1)&3) undoes the swizzle.
    // Conflict-free (SQ_LDS_BANK_CONFLICT == 0 measured R0/R1/R2).
    int aoff[8], boff[4];
    const int kc = lane >> 4;
#pragma unroll
    for (int i = 0; i < 8; ++i) {
        int r = wm * 128 + i * 16 + (lane & 15);
        aoff[i] = r * 64 + ((kc ^ ((r >> 1) & 3)) * 16);
    }
#pragma unroll
    for (int j = 0; j < 4; ++j) {
        int r = wn * 64 + j * 16 + (lane & 15);
        boff[j] = 16384 + r * 64 + ((kc ^ ((r >> 1) & 3)) * 16);
    }

    i32x4 acc[8][4] = {};

    // Prologue: stage tile 0 -> buf0, tile 1 -> buf1; confirm tile 0 only
    // (vmcnt(4) leaves tile 1's 4 units in flight).
    gload16_lds(gA0,      smem + dA0);
    gload16_lds(gA1,      smem + dA1);
    gload16_lds(gB0,      smem + dB0);
    gload16_lds(gB1,      smem + dB1);
    gload16_lds(gA0 + 64, smem + 32768 + dA0);
    gload16_lds(gA1 + 64, smem + 32768 + dA1);
    gload16_lds(gB0 + 64, smem + 32768 + dB0);
    gload16_lds(gB1 + 64, smem + 32768 + dB1);
    WAITV(4);

    // Main loop: tiles 0..59 (buffer index = kt%3, statically unrolled x3),
    // each staging tile kt+2 with counted vmcnt(4). Tiles 60/61 stage 62/63.
    // Tile 62: no staging, vmcnt(0) drains tile 63's units. Tile 63: bare.
    for (int kt = 0; kt < 60; kt += 3) {
        TILE1(0, 2, (kt + 2) * 64, 1, WAITV(4));
        TILE1(1, 0, (kt + 3) * 64, 1, WAITV(4));
        TILE1(2, 1, (kt + 4) * 64, 1, WAITV(4));
    }
    TILE1(0, 2, 62 * 64, 1, WAITV(4));   // tile 60
    TILE1(1, 0, 63 * 64, 1, WAITV(4));   // tile 61
    TILE1(2, 0, 0,       0, WAITV(0));   // tile 62 (drain stage(63))
    TILE1(0, 0, 0,       0, (void)0);    // tile 63

    // Epilogue: out = fp32( bf16(acc) * bf16(xs*ws) ) + bias
    float amax = __uint_as_float(*amax_u);
    float xs = (amax == 0.0f) ? 1.0f : (amax / 127.0f);
    float cs = bf16_rne(xs * wscale_p[0]);

    // C/D layout (16x16): col = lane&15, row = (lane>>4)*4 + reg
#pragma unroll
    for (int j = 0; j < 4; ++j) {
        int n = tileN + wn * 64 + j * 16 + (lane & 15);
        float bz = bias[n];
#pragma unroll
        for (int i = 0; i < 8; ++i) {
            int row0 = tileM + wm * 128 + i * 16 + (lane >> 4) * 4;
#pragma unroll
            for (int r = 0; r < 4; ++r) {
                float v = bf16_rne((float)acc[i][j][r]);
                float p = bf16_rne(v * cs);
                // nontemporal: don't let the 128MB output evict A/B in L2/LLC
                __builtin_nontemporal_store(
                    p + bz, &out[(size_t)(row0 + r) * OUT_F + n]);
            }
        }
    }
}

// ---------------- launch ----------------
extern "C" void kernel_launch(void* const* d_in, const int* in_sizes, int n_in,
                              void* d_out, int out_size, void* d_ws,
                              size_t ws_size, hipStream_t stream) {
    const float* x = (const float*)d_in[0];
    const int* w_int = (const int*)d_in[1];
    const float* w_scale = (const float*)d_in[2];
    const float* bias = (const float*)d_in[3];
    float* out = (float*)d_out;

    unsigned char* ws = (unsigned char*)d_ws;
    unsigned int* amax_u = (unsigned int*)ws;                         // 4 B
    signed char* w8 = (signed char*)(ws + 64);                        // 16 MiB
    signed char* x8 = (signed char*)(ws + 64 + (size_t)OUT_F * IN_F); // 32 MiB

    hipMemsetAsync(amax_u, 0, 4, stream);

    const int n_x4 = MDIM * IN_F / 4;   // 8,388,608 float4
    const int n_w4 = OUT_F * IN_F / 4;  // 4,194,304 int4

    amax_kernel<<<4096, 256, 0, stream>>>(x, n_x4, amax_u);
    prep_kernel<<<(n_x4 + n_w4) / 256, 256, 0, stream>>>(
        x, w_int, x8, w8, amax_u, n_x4, n_w4);

    const int nblocks = (MDIM / 256) * (OUT_F / 256);  // 512
    gemm_i8_kernel<<<nblocks, 512, 0, stream>>>(x8, w8, amax_u, w_scale, bias,
                                                out);
}